// Round 4
// baseline (1354.750 us; speedup 1.0000x reference)
//
#include <hip/hip_runtime.h>

#define N_USERC 50000
#define N_ITEMC 100000
#define NN      150000      // total nodes
#define DD      64
#define NLAYER  3
#define NNZC    2400000
#define BB      4096
#define NRID    (3*BB)      // 12288 gathered output rows
#define NBLK    147         // ceil((NN+1)/1024)

typedef unsigned short ushort_t;
typedef __attribute__((ext_vector_type(4))) float float4v;

static __device__ __forceinline__ float bf2f(ushort_t b) {
    unsigned int u = ((unsigned int)b) << 16;
    return __uint_as_float(u);
}
static __device__ __forceinline__ ushort_t f2bf(float f) {
    unsigned int u = __float_as_uint(f);
    u = u + 0x7FFFu + ((u >> 16) & 1u);   // round-to-nearest-even
    return (ushort_t)(u >> 16);
}

// ---- dtype sniff: flag=1 if float inputs are packed bf16, 0 if fp32 ----
// (round-1 vs round-2 NaN differential already proved fp32; kept as a cheap hedge)
__global__ __launch_bounds__(64) void k_sniff(const unsigned int* __restrict__ ue_words,
                                              int* __restrict__ flag) {
    int lane = threadIdx.x;
    int cnt = 0;
    for (int i = 0; i < 4; i++) {
        unsigned int w = ue_words[lane * 4 + i];
        unsigned int lo = w & 0xFFFFu;
        unsigned int ex = (lo >> 7) & 0xFF;
        if (ex >= 100 && ex <= 132) cnt++;
    }
    for (int m = 1; m < 64; m <<= 1) cnt += __shfl_xor(cnt, m, 64);
    if (lane == 0) *flag = (cnt >= 128) ? 1 : 0;
}

// ---- init: E fp32 from inputs ----
__global__ __launch_bounds__(256) void k_init(const void* __restrict__ ue,
                                              const void* __restrict__ ie,
                                              const int* __restrict__ flag,
                                              float* __restrict__ E) {
    int idx = blockIdx.x * 256 + threadIdx.x;           // over NN*64
    if (idx >= NN * DD) return;
    int row = idx >> 6;
    bool isU = row < N_USERC;
    int si = isU ? idx : idx - N_USERC * DD;
    float v;
    if (*flag) {
        v = bf2f(isU ? ((const ushort_t*)ue)[si] : ((const ushort_t*)ie)[si]);
    } else {
        v = isU ? ((const float*)ue)[si] : ((const float*)ie)[si];
    }
    E[idx] = v;
}

__global__ __launch_bounds__(256) void k_zero(int* __restrict__ cnt) {
    int i = blockIdx.x * 256 + threadIdx.x;
    if (i < NN) cnt[i] = 0;
}

__global__ __launch_bounds__(256) void k_hist(const int* __restrict__ rows,
                                              int* __restrict__ cnt) {
    int e = blockIdx.x * 256 + threadIdx.x;
    if (e < NNZC) atomicAdd(&cnt[rows[e]], 1);
}

__global__ __launch_bounds__(1024) void k_scan1(const int* __restrict__ cnt,
                                                int* __restrict__ tmp_ex,
                                                int* __restrict__ partials) {
    __shared__ int s[1024];
    int t = threadIdx.x;
    int i = blockIdx.x * 1024 + t;
    int v = (i < NN) ? cnt[i] : 0;
    s[t] = v; __syncthreads();
    for (int off = 1; off < 1024; off <<= 1) {
        int x = (t >= off) ? s[t - off] : 0;
        __syncthreads();
        s[t] += x;
        __syncthreads();
    }
    tmp_ex[i] = s[t] - v;                      // exclusive
    if (t == 1023) partials[blockIdx.x] = s[t];
}

__global__ __launch_bounds__(256) void k_scan2(int* __restrict__ partials) {
    __shared__ int s[256];
    int t = threadIdx.x;
    int v = (t < NBLK) ? partials[t] : 0;
    s[t] = v; __syncthreads();
    for (int off = 1; off < 256; off <<= 1) {
        int x = (t >= off) ? s[t - off] : 0;
        __syncthreads();
        s[t] += x;
        __syncthreads();
    }
    if (t < NBLK) partials[t] = s[t] - v;      // exclusive
}

// in-place: row_ptr[i] = tmp_ex[i] + partials[i>>10]  (elementwise, safe in-place)
__global__ __launch_bounds__(256) void k_scan3(int* __restrict__ row_ptr,
                                               const int* __restrict__ partials,
                                               int* __restrict__ cursor) {
    int i = blockIdx.x * 256 + threadIdx.x;
    if (i <= NN) {
        int rp = row_ptr[i] + partials[i >> 10];
        row_ptr[i] = rp;
        cursor[i]  = rp;
    }
}

__global__ __launch_bounds__(256) void k_scatter(const int* __restrict__ rows,
                                                 const int* __restrict__ cols,
                                                 const void* __restrict__ vals,
                                                 const int* __restrict__ flag,
                                                 int* __restrict__ cursor,
                                                 int2* __restrict__ ep) {
    int e = blockIdx.x * 256 + threadIdx.x;
    if (e >= NNZC) return;
    int r = rows[e];
    int c = cols[e];
    float v = (*flag) ? bf2f(((const ushort_t*)vals)[e]) : ((const float*)vals)[e];
    int p = atomicAdd(&cursor[r], 1);
    ep[p] = make_int2(c, __float_as_int(v));
}

// ---- SpMM: one wave per row, lane = feature dim; fp32 end-to-end ----
__global__ __launch_bounds__(256) void k_spmm(const int* __restrict__ row_ptr,
                                              const int2* __restrict__ ep,
                                              const float* __restrict__ E,
                                              float* __restrict__ LE) {
    int r = blockIdx.x * 4 + (threadIdx.x >> 6);
    if (r >= NN) return;
    int lane = threadIdx.x & 63;
    int s = row_ptr[r], e = row_ptr[r + 1];
    float acc = 0.f;
    for (int i = s; i < e; i++) {
        int2 pv = ep[i];
        acc += __int_as_float(pv.y) * E[(size_t)pv.x * DD + lane];
    }
    LE[(size_t)r * DD + lane] = acc;
}

// ---- dense (pure fp32 VALU): h = (LE+E)@W1 + (LE*E)@W2 + b1 + b2, leaky, E:=h
// One block = 16 rows (4 waves x 4 rows). Lane = (rg = lane>>4 row, cg = lane&15 -> cols cg*4..+3).
__global__ __launch_bounds__(256) void k_dense(const float* __restrict__ LE,
                                               float* __restrict__ E,
                                               const void* __restrict__ W1b,
                                               const void* __restrict__ W2b,
                                               const void* __restrict__ b1b,
                                               const void* __restrict__ b2b,
                                               const int* __restrict__ flag,
                                               int layer) {
    __shared__ __align__(16) float w1s[4096];
    __shared__ __align__(16) float w2s[4096];
    __shared__ __align__(16) float xs[4][2][4][64];   // [wave][x1|x2][rowslot][k]

    int tid  = threadIdx.x;
    int isbf = *flag;
    for (int i = tid; i < 4096; i += 256) {
        size_t off = (size_t)layer * 4096 + i;
        w1s[i] = isbf ? bf2f(((const ushort_t*)W1b)[off]) : ((const float*)W1b)[off];
        w2s[i] = isbf ? bf2f(((const ushort_t*)W2b)[off]) : ((const float*)W2b)[off];
    }

    int lane = tid & 63, wv = tid >> 6;
    int rg = lane >> 4, cg = lane & 15;

    float bsum[4];
#pragma unroll
    for (int j = 0; j < 4; j++) {
        size_t off = (size_t)layer * 64 + cg * 4 + j;
        float v1 = isbf ? bf2f(((const ushort_t*)b1b)[off]) : ((const float*)b1b)[off];
        float v2 = isbf ? bf2f(((const ushort_t*)b2b)[off]) : ((const float*)b2b)[off];
        bsum[j] = v1 + v2;
    }

    int r0 = blockIdx.x * 16 + wv * 4;     // 9375 blocks * 16 = 150000 exact

    // stage x1/x2 for 4 rows: lane covers flat elems lane*4..lane*4+3 of the 4x64 block
    const float4v* LEp = (const float4v*)(LE + (size_t)r0 * DD);
    const float4v* Ep  = (const float4v*)(E  + (size_t)r0 * DD);
    float4v l4 = LEp[lane];
    float4v e4 = Ep[lane];
    float4v x1, x2;
#pragma unroll
    for (int u = 0; u < 4; u++) { x1[u] = l4[u] + e4[u]; x2[u] = l4[u] * e4[u]; }
    int srow = lane >> 4, scol = (lane & 15) * 4;
    *(float4v*)&xs[wv][0][srow][scol] = x1;
    *(float4v*)&xs[wv][1][srow][scol] = x2;
    __syncthreads();   // also covers w1s/w2s staging

    float4v acc = {0.f, 0.f, 0.f, 0.f};
#pragma unroll
    for (int k4 = 0; k4 < 64; k4 += 4) {
        float4v x1b = *(const float4v*)&xs[wv][0][rg][k4];
        float4v x2b = *(const float4v*)&xs[wv][1][rg][k4];
#pragma unroll
        for (int u = 0; u < 4; u++) {
            float4v w1v = *(const float4v*)&w1s[(k4 + u) * 64 + cg * 4];
            float4v w2v = *(const float4v*)&w2s[(k4 + u) * 64 + cg * 4];
            acc += x1b[u] * w1v + x2b[u] * w2v;
        }
    }

    float4v st;
#pragma unroll
    for (int u = 0; u < 4; u++) {
        float h = acc[u] + bsum[u];
        st[u] = (h >= 0.f) ? h : 0.2f * h;
    }
    *(float4v*)(E + (size_t)(r0 + rg) * DD + cg * 4) = st;
}

static __device__ __forceinline__ int rid_to_node(int rid,
                                                  const int* users, const int* pos, const int* neg) {
    if (rid < BB)      return users[rid] - 1;
    if (rid < 2 * BB)  return N_USERC + pos[rid - BB] - 1;
    return N_USERC + neg[rid - 2 * BB] - 1;
}

// ---- slice 0 of output: raw initial embedding (fp32) of gathered rows ----
__global__ __launch_bounds__(256) void k_outslice0(const float* __restrict__ E,
                                                   const int* __restrict__ users,
                                                   const int* __restrict__ pos,
                                                   const int* __restrict__ neg,
                                                   float* __restrict__ out) {
    int rid  = blockIdx.x * 4 + (threadIdx.x >> 6);
    int lane = threadIdx.x & 63;
    if (rid >= NRID) return;
    int node = rid_to_node(rid, users, pos, neg);
    out[(size_t)rid * 256 + lane] = E[(size_t)node * DD + lane];
}

// ---- slice l+1: normalized current E of gathered rows (fp32) ----
__global__ __launch_bounds__(256) void k_outnorm(const float* __restrict__ E,
                                                 const int* __restrict__ users,
                                                 const int* __restrict__ pos,
                                                 const int* __restrict__ neg,
                                                 float* __restrict__ out,
                                                 int cbase) {
    int rid  = blockIdx.x * 4 + (threadIdx.x >> 6);
    int lane = threadIdx.x & 63;
    if (rid >= NRID) return;
    int node = rid_to_node(rid, users, pos, neg);
    float v = E[(size_t)node * DD + lane];
    float p2 = v * v;
    for (int m = 1; m < 64; m <<= 1) p2 += __shfl_xor(p2, m, 64);
    float nr = fmaxf(sqrtf(p2), 1e-12f);
    out[(size_t)rid * 256 + cbase + lane] = v / nr;
}

extern "C" void kernel_launch(void* const* d_in, const int* in_sizes, int n_in,
                              void* d_out, int out_size, void* d_ws, size_t ws_size,
                              hipStream_t stream) {
    const void* ue   = d_in[0];
    const void* ie   = d_in[1];
    const void* ev   = d_in[2];
    const void* W1   = d_in[3];
    const void* b1   = d_in[4];
    const void* W2   = d_in[5];
    const void* b2   = d_in[6];
    const int*  ei   = (const int*)d_in[7];
    const int*  usr  = (const int*)d_in[8];
    const int*  posi = (const int*)d_in[9];
    const int*  negi = (const int*)d_in[10];
    float*      out  = (float*)d_out;          // reference output dtype = fp32

    const int* rows = ei;
    const int* cols = ei + NNZC;

    // workspace carve — total ~98 MB
    char* w = (char*)d_ws;
    float*  E       = (float*)w;   w += (size_t)NN * DD * 4;       // 38.4 MB
    float*  LE      = (float*)w;   w += (size_t)NN * DD * 4;       // 38.4 MB
    int2*   ep      = (int2*)w;    w += (size_t)NNZC * 8;          // 19.2 MB
    int*    row_ptr = (int*)w;     w += (size_t)NBLK * 1024 * 4;   // 602112 B (doubles as tmp_ex)
    int*    cursor  = (int*)w;     w += 600064;
    int*    cnt     = (int*)w;     w += 600064;
    int*    partials= (int*)w;     w += 1024;
    int*    flag    = (int*)w;     w += 256;

    k_sniff<<<1, 64, 0, stream>>>((const unsigned int*)ue, flag);
    k_init<<<37500, 256, 0, stream>>>(ue, ie, flag, E);
    k_zero<<<586, 256, 0, stream>>>(cnt);
    k_hist<<<9375, 256, 0, stream>>>(rows, cnt);
    k_scan1<<<NBLK, 1024, 0, stream>>>(cnt, row_ptr, partials);   // row_ptr <- per-block exclusive
    k_scan2<<<1, 256, 0, stream>>>(partials);
    k_scan3<<<587, 256, 0, stream>>>(row_ptr, partials, cursor);
    k_scatter<<<9375, 256, 0, stream>>>(rows, cols, ev, flag, cursor, ep);

    k_outslice0<<<3072, 256, 0, stream>>>(E, usr, posi, negi, out);

    for (int l = 0; l < NLAYER; l++) {
        k_spmm<<<37500, 256, 0, stream>>>(row_ptr, ep, E, LE);
        k_dense<<<9375, 256, 0, stream>>>(LE, E, W1, W2, b1, b2, flag, l);
        k_outnorm<<<3072, 256, 0, stream>>>(E, usr, posi, negi, out, 64 * (l + 1));
    }
}

// Round 5
// 966.400 us; speedup vs baseline: 1.4019x; 1.4019x over previous
//
#include <hip/hip_runtime.h>

#define N_USERC 50000
#define N_ITEMC 100000
#define NN      150000      // total nodes
#define DD      64
#define NLAYER  3
#define NNZC    2400000
#define BB      4096
#define NRID    (3*BB)      // 12288 gathered output rows
#define NBLK    147         // ceil((NN+1)/1024)

typedef unsigned short ushort_t;
typedef __attribute__((ext_vector_type(4))) float float4v;

static __device__ __forceinline__ float bf2f(ushort_t b) {
    unsigned int u = ((unsigned int)b) << 16;
    return __uint_as_float(u);
}

// ---- dtype sniff: flag=1 if float inputs are packed bf16, 0 if fp32 ----
// (round-1 vs round-2 NaN differential proved fp32; kept as a cheap hedge)
__global__ __launch_bounds__(64) void k_sniff(const unsigned int* __restrict__ ue_words,
                                              int* __restrict__ flag) {
    int lane = threadIdx.x;
    int cnt = 0;
    for (int i = 0; i < 4; i++) {
        unsigned int w = ue_words[lane * 4 + i];
        unsigned int lo = w & 0xFFFFu;
        unsigned int ex = (lo >> 7) & 0xFF;
        if (ex >= 100 && ex <= 132) cnt++;
    }
    for (int m = 1; m < 64; m <<= 1) cnt += __shfl_xor(cnt, m, 64);
    if (lane == 0) *flag = (cnt >= 128) ? 1 : 0;
}

// ---- init: E fp32 from inputs ----
__global__ __launch_bounds__(256) void k_init(const void* __restrict__ ue,
                                              const void* __restrict__ ie,
                                              const int* __restrict__ flag,
                                              float* __restrict__ E) {
    int idx = blockIdx.x * 256 + threadIdx.x;           // over NN*64
    if (idx >= NN * DD) return;
    int row = idx >> 6;
    bool isU = row < N_USERC;
    int si = isU ? idx : idx - N_USERC * DD;
    float v;
    if (*flag) {
        v = bf2f(isU ? ((const ushort_t*)ue)[si] : ((const ushort_t*)ie)[si]);
    } else {
        v = isU ? ((const float*)ue)[si] : ((const float*)ie)[si];
    }
    E[idx] = v;
}

__global__ __launch_bounds__(256) void k_zero(int* __restrict__ cnt) {
    int i = blockIdx.x * 256 + threadIdx.x;
    if (i < NN) cnt[i] = 0;
}

__global__ __launch_bounds__(256) void k_hist(const int* __restrict__ rows,
                                              int* __restrict__ cnt) {
    int e = blockIdx.x * 256 + threadIdx.x;
    if (e < NNZC) atomicAdd(&cnt[rows[e]], 1);
}

__global__ __launch_bounds__(1024) void k_scan1(const int* __restrict__ cnt,
                                                int* __restrict__ tmp_ex,
                                                int* __restrict__ partials) {
    __shared__ int s[1024];
    int t = threadIdx.x;
    int i = blockIdx.x * 1024 + t;
    int v = (i < NN) ? cnt[i] : 0;
    s[t] = v; __syncthreads();
    for (int off = 1; off < 1024; off <<= 1) {
        int x = (t >= off) ? s[t - off] : 0;
        __syncthreads();
        s[t] += x;
        __syncthreads();
    }
    tmp_ex[i] = s[t] - v;                      // exclusive
    if (t == 1023) partials[blockIdx.x] = s[t];
}

__global__ __launch_bounds__(256) void k_scan2(int* __restrict__ partials) {
    __shared__ int s[256];
    int t = threadIdx.x;
    int v = (t < NBLK) ? partials[t] : 0;
    s[t] = v; __syncthreads();
    for (int off = 1; off < 256; off <<= 1) {
        int x = (t >= off) ? s[t - off] : 0;
        __syncthreads();
        s[t] += x;
        __syncthreads();
    }
    if (t < NBLK) partials[t] = s[t] - v;      // exclusive
}

// in-place: row_ptr[i] = tmp_ex[i] + partials[i>>10]  (elementwise, safe in-place)
__global__ __launch_bounds__(256) void k_scan3(int* __restrict__ row_ptr,
                                               const int* __restrict__ partials,
                                               int* __restrict__ cursor) {
    int i = blockIdx.x * 256 + threadIdx.x;
    if (i <= NN) {
        int rp = row_ptr[i] + partials[i >> 10];
        row_ptr[i] = rp;
        cursor[i]  = rp;
    }
}

__global__ __launch_bounds__(256) void k_scatter(const int* __restrict__ rows,
                                                 const int* __restrict__ cols,
                                                 const void* __restrict__ vals,
                                                 const int* __restrict__ flag,
                                                 int* __restrict__ cursor,
                                                 int2* __restrict__ ep) {
    int e = blockIdx.x * 256 + threadIdx.x;
    if (e >= NNZC) return;
    int r = rows[e];
    int c = cols[e];
    float v = (*flag) ? bf2f(((const ushort_t*)vals)[e]) : ((const float*)vals)[e];
    int p = atomicAdd(&cursor[r], 1);
    ep[p] = make_int2(c, __float_as_int(v));
}

// ---- SpMM: one wave per row, lane = feature dim; fp32 end-to-end.
// readfirstlane makes row bounds scalar -> ep[] loads go down the SMEM path;
// 4-wide clamped unroll keeps 4 independent E-row gathers in flight (no serial tail).
__global__ __launch_bounds__(256) void k_spmm(const int* __restrict__ row_ptr,
                                              const int2* __restrict__ ep,
                                              const float* __restrict__ E,
                                              float* __restrict__ LE) {
    int wv = threadIdx.x >> 6;
    int r = blockIdx.x * 4 + wv;               // 37500*4 = 150000 exact
    int lane = threadIdx.x & 63;
    int s = __builtin_amdgcn_readfirstlane(row_ptr[r]);
    int e = __builtin_amdgcn_readfirstlane(row_ptr[r + 1]);
    float acc = 0.f;
    for (int i = s; i < e; i += 4) {
        int i0 = i,     i1 = i + 1, i2 = i + 2, i3 = i + 3;
        // clamp out-of-range to a valid uniform index; zero the weight
        int j0 = i0;                        // always valid (i < e)
        int j1 = (i1 < e) ? i1 : s;
        int j2 = (i2 < e) ? i2 : s;
        int j3 = (i3 < e) ? i3 : s;
        int2 p0 = ep[j0];
        int2 p1 = ep[j1];
        int2 p2 = ep[j2];
        int2 p3 = ep[j3];
        float w0 = __int_as_float(p0.y);
        float w1 = (i1 < e) ? __int_as_float(p1.y) : 0.f;
        float w2 = (i2 < e) ? __int_as_float(p2.y) : 0.f;
        float w3 = (i3 < e) ? __int_as_float(p3.y) : 0.f;
        float f0 = E[(size_t)p0.x * DD + lane];
        float f1 = E[(size_t)p1.x * DD + lane];
        float f2 = E[(size_t)p2.x * DD + lane];
        float f3 = E[(size_t)p3.x * DD + lane];
        acc += w0 * f0;
        acc += w1 * f1;
        acc += w2 * f2;
        acc += w3 * f3;
    }
    LE[(size_t)r * DD + lane] = acc;
}

// ---- dense (pure fp32 VALU): h = (LE+E)@W1 + (LE*E)@W2 + b1 + b2, leaky, E:=h
// One block = 16 rows (4 waves x 4 rows). Lane = (rg = lane>>4 row, cg = lane&15 -> cols cg*4..+3).
__global__ __launch_bounds__(256) void k_dense(const float* __restrict__ LE,
                                               float* __restrict__ E,
                                               const void* __restrict__ W1b,
                                               const void* __restrict__ W2b,
                                               const void* __restrict__ b1b,
                                               const void* __restrict__ b2b,
                                               const int* __restrict__ flag,
                                               int layer) {
    __shared__ __align__(16) float w1s[4096];
    __shared__ __align__(16) float w2s[4096];
    __shared__ __align__(16) float xs[4][2][4][64];   // [wave][x1|x2][rowslot][k]

    int tid  = threadIdx.x;
    int isbf = *flag;
    for (int i = tid; i < 4096; i += 256) {
        size_t off = (size_t)layer * 4096 + i;
        w1s[i] = isbf ? bf2f(((const ushort_t*)W1b)[off]) : ((const float*)W1b)[off];
        w2s[i] = isbf ? bf2f(((const ushort_t*)W2b)[off]) : ((const float*)W2b)[off];
    }

    int lane = tid & 63, wv = tid >> 6;
    int rg = lane >> 4, cg = lane & 15;

    float bsum[4];
#pragma unroll
    for (int j = 0; j < 4; j++) {
        size_t off = (size_t)layer * 64 + cg * 4 + j;
        float v1 = isbf ? bf2f(((const ushort_t*)b1b)[off]) : ((const float*)b1b)[off];
        float v2 = isbf ? bf2f(((const ushort_t*)b2b)[off]) : ((const float*)b2b)[off];
        bsum[j] = v1 + v2;
    }

    int r0 = blockIdx.x * 16 + wv * 4;     // 9375 blocks * 16 = 150000 exact

    // stage x1/x2 for 4 rows: lane covers flat elems lane*4..lane*4+3 of the 4x64 block
    const float4v* LEp = (const float4v*)(LE + (size_t)r0 * DD);
    const float4v* Ep  = (const float4v*)(E  + (size_t)r0 * DD);
    float4v l4 = LEp[lane];
    float4v e4 = Ep[lane];
    float4v x1, x2;
#pragma unroll
    for (int u = 0; u < 4; u++) { x1[u] = l4[u] + e4[u]; x2[u] = l4[u] * e4[u]; }
    int srow = lane >> 4, scol = (lane & 15) * 4;
    *(float4v*)&xs[wv][0][srow][scol] = x1;
    *(float4v*)&xs[wv][1][srow][scol] = x2;
    __syncthreads();   // also covers w1s/w2s staging

    float4v acc = {0.f, 0.f, 0.f, 0.f};
#pragma unroll
    for (int k4 = 0; k4 < 64; k4 += 4) {
        float4v x1b = *(const float4v*)&xs[wv][0][rg][k4];
        float4v x2b = *(const float4v*)&xs[wv][1][rg][k4];
#pragma unroll
        for (int u = 0; u < 4; u++) {
            float4v w1v = *(const float4v*)&w1s[(k4 + u) * 64 + cg * 4];
            float4v w2v = *(const float4v*)&w2s[(k4 + u) * 64 + cg * 4];
            acc += x1b[u] * w1v + x2b[u] * w2v;
        }
    }

    float4v st;
#pragma unroll
    for (int u = 0; u < 4; u++) {
        float h = acc[u] + bsum[u];
        st[u] = (h >= 0.f) ? h : 0.2f * h;
    }
    *(float4v*)(E + (size_t)(r0 + rg) * DD + cg * 4) = st;
}

static __device__ __forceinline__ int rid_to_node(int rid,
                                                  const int* users, const int* pos, const int* neg) {
    if (rid < BB)      return users[rid] - 1;
    if (rid < 2 * BB)  return N_USERC + pos[rid - BB] - 1;
    return N_USERC + neg[rid - 2 * BB] - 1;
}

// ---- slice 0 of output: raw initial embedding (fp32) of gathered rows ----
__global__ __launch_bounds__(256) void k_outslice0(const float* __restrict__ E,
                                                   const int* __restrict__ users,
                                                   const int* __restrict__ pos,
                                                   const int* __restrict__ neg,
                                                   float* __restrict__ out) {
    int rid  = blockIdx.x * 4 + (threadIdx.x >> 6);
    int lane = threadIdx.x & 63;
    if (rid >= NRID) return;
    int node = rid_to_node(rid, users, pos, neg);
    out[(size_t)rid * 256 + lane] = E[(size_t)node * DD + lane];
}

// ---- slice l+1: normalized current E of gathered rows (fp32) ----
__global__ __launch_bounds__(256) void k_outnorm(const float* __restrict__ E,
                                                 const int* __restrict__ users,
                                                 const int* __restrict__ pos,
                                                 const int* __restrict__ neg,
                                                 float* __restrict__ out,
                                                 int cbase) {
    int rid  = blockIdx.x * 4 + (threadIdx.x >> 6);
    int lane = threadIdx.x & 63;
    if (rid >= NRID) return;
    int node = rid_to_node(rid, users, pos, neg);
    float v = E[(size_t)node * DD + lane];
    float p2 = v * v;
    for (int m = 1; m < 64; m <<= 1) p2 += __shfl_xor(p2, m, 64);
    float nr = fmaxf(sqrtf(p2), 1e-12f);
    out[(size_t)rid * 256 + cbase + lane] = v / nr;
}

extern "C" void kernel_launch(void* const* d_in, const int* in_sizes, int n_in,
                              void* d_out, int out_size, void* d_ws, size_t ws_size,
                              hipStream_t stream) {
    const void* ue   = d_in[0];
    const void* ie   = d_in[1];
    const void* ev   = d_in[2];
    const void* W1   = d_in[3];
    const void* b1   = d_in[4];
    const void* W2   = d_in[5];
    const void* b2   = d_in[6];
    const int*  ei   = (const int*)d_in[7];
    const int*  usr  = (const int*)d_in[8];
    const int*  posi = (const int*)d_in[9];
    const int*  negi = (const int*)d_in[10];
    float*      out  = (float*)d_out;          // reference output dtype = fp32

    const int* rows = ei;
    const int* cols = ei + NNZC;

    // workspace carve — total ~98 MB
    char* w = (char*)d_ws;
    float*  E       = (float*)w;   w += (size_t)NN * DD * 4;       // 38.4 MB
    float*  LE      = (float*)w;   w += (size_t)NN * DD * 4;       // 38.4 MB
    int2*   ep      = (int2*)w;    w += (size_t)NNZC * 8;          // 19.2 MB
    int*    row_ptr = (int*)w;     w += (size_t)NBLK * 1024 * 4;   // 602112 B (doubles as tmp_ex)
    int*    cursor  = (int*)w;     w += 600064;
    int*    cnt     = (int*)w;     w += 600064;
    int*    partials= (int*)w;     w += 1024;
    int*    flag    = (int*)w;     w += 256;

    k_sniff<<<1, 64, 0, stream>>>((const unsigned int*)ue, flag);
    k_init<<<37500, 256, 0, stream>>>(ue, ie, flag, E);
    k_zero<<<586, 256, 0, stream>>>(cnt);
    k_hist<<<9375, 256, 0, stream>>>(rows, cnt);
    k_scan1<<<NBLK, 1024, 0, stream>>>(cnt, row_ptr, partials);   // row_ptr <- per-block exclusive
    k_scan2<<<1, 256, 0, stream>>>(partials);
    k_scan3<<<587, 256, 0, stream>>>(row_ptr, partials, cursor);
    k_scatter<<<9375, 256, 0, stream>>>(rows, cols, ev, flag, cursor, ep);

    k_outslice0<<<3072, 256, 0, stream>>>(E, usr, posi, negi, out);

    for (int l = 0; l < NLAYER; l++) {
        k_spmm<<<37500, 256, 0, stream>>>(row_ptr, ep, E, LE);
        k_dense<<<9375, 256, 0, stream>>>(LE, E, W1, W2, b1, b2, flag, l);
        k_outnorm<<<3072, 256, 0, stream>>>(E, usr, posi, negi, out, 64 * (l + 1));
    }
}

// Round 6
// 943.874 us; speedup vs baseline: 1.4353x; 1.0239x over previous
//
#include <hip/hip_runtime.h>

#define N_USERC 50000
#define N_ITEMC 100000
#define NN      150000      // total nodes
#define DD      64
#define NLAYER  3
#define NNZC    2400000
#define BB      4096
#define NRID    (3*BB)      // 12288 gathered output rows
#define NBLK    147         // ceil((NN+1)/1024)

typedef unsigned short ushort_t;
typedef __attribute__((ext_vector_type(4))) float float4v;

static __device__ __forceinline__ float bf2f(ushort_t b) {
    unsigned int u = ((unsigned int)b) << 16;
    return __uint_as_float(u);
}

// ---- dtype sniff: flag=1 if float inputs are packed bf16, 0 if fp32 ----
// (round-1 vs round-2 NaN differential proved fp32; kept as a cheap hedge)
__global__ __launch_bounds__(64) void k_sniff(const unsigned int* __restrict__ ue_words,
                                              int* __restrict__ flag) {
    int lane = threadIdx.x;
    int cnt = 0;
    for (int i = 0; i < 4; i++) {
        unsigned int w = ue_words[lane * 4 + i];
        unsigned int lo = w & 0xFFFFu;
        unsigned int ex = (lo >> 7) & 0xFF;
        if (ex >= 100 && ex <= 132) cnt++;
    }
    for (int m = 1; m < 64; m <<= 1) cnt += __shfl_xor(cnt, m, 64);
    if (lane == 0) *flag = (cnt >= 128) ? 1 : 0;
}

// ---- init: E fp32 from inputs ----
__global__ __launch_bounds__(256) void k_init(const void* __restrict__ ue,
                                              const void* __restrict__ ie,
                                              const int* __restrict__ flag,
                                              float* __restrict__ E) {
    int idx = blockIdx.x * 256 + threadIdx.x;           // over NN*64
    if (idx >= NN * DD) return;
    int row = idx >> 6;
    bool isU = row < N_USERC;
    int si = isU ? idx : idx - N_USERC * DD;
    float v;
    if (*flag) {
        v = bf2f(isU ? ((const ushort_t*)ue)[si] : ((const ushort_t*)ie)[si]);
    } else {
        v = isU ? ((const float*)ue)[si] : ((const float*)ie)[si];
    }
    E[idx] = v;
}

__global__ __launch_bounds__(256) void k_zero(int* __restrict__ cnt) {
    int i = blockIdx.x * 256 + threadIdx.x;
    if (i < NN) cnt[i] = 0;
}

__global__ __launch_bounds__(256) void k_hist(const int* __restrict__ rows,
                                              int* __restrict__ cnt) {
    int e = blockIdx.x * 256 + threadIdx.x;
    if (e < NNZC) atomicAdd(&cnt[rows[e]], 1);
}

__global__ __launch_bounds__(1024) void k_scan1(const int* __restrict__ cnt,
                                                int* __restrict__ tmp_ex,
                                                int* __restrict__ partials) {
    __shared__ int s[1024];
    int t = threadIdx.x;
    int i = blockIdx.x * 1024 + t;
    int v = (i < NN) ? cnt[i] : 0;
    s[t] = v; __syncthreads();
    for (int off = 1; off < 1024; off <<= 1) {
        int x = (t >= off) ? s[t - off] : 0;
        __syncthreads();
        s[t] += x;
        __syncthreads();
    }
    tmp_ex[i] = s[t] - v;                      // exclusive
    if (t == 1023) partials[blockIdx.x] = s[t];
}

__global__ __launch_bounds__(256) void k_scan2(int* __restrict__ partials) {
    __shared__ int s[256];
    int t = threadIdx.x;
    int v = (t < NBLK) ? partials[t] : 0;
    s[t] = v; __syncthreads();
    for (int off = 1; off < 256; off <<= 1) {
        int x = (t >= off) ? s[t - off] : 0;
        __syncthreads();
        s[t] += x;
        __syncthreads();
    }
    if (t < NBLK) partials[t] = s[t] - v;      // exclusive
}

// in-place: row_ptr[i] = tmp_ex[i] + partials[i>>10]  (elementwise, safe in-place)
__global__ __launch_bounds__(256) void k_scan3(int* __restrict__ row_ptr,
                                               const int* __restrict__ partials,
                                               int* __restrict__ cursor) {
    int i = blockIdx.x * 256 + threadIdx.x;
    if (i <= NN) {
        int rp = row_ptr[i] + partials[i >> 10];
        row_ptr[i] = rp;
        cursor[i]  = rp;
    }
}

// ---- scatter, region-confined: 10 passes over row-regions (row>>14) so the
// concurrently-written ep window is ~2.1 MB (L2-resident -> full-line evictions,
// kills the 8x write-allocate amplification seen in round 5: WRITE_SIZE 149 MB
// for a 19.2 MB payload). Edge data preloaded to registers; pass loop costs no
// extra global reads. __syncthreads keeps blocks pass-aligned.
__global__ __launch_bounds__(256) void k_scatter(const int* __restrict__ rows,
                                                 const int* __restrict__ cols,
                                                 const void* __restrict__ vals,
                                                 const int* __restrict__ flag,
                                                 int* __restrict__ cursor,
                                                 int2* __restrict__ ep) {
    int e = blockIdx.x * 256 + threadIdx.x;
    int r = -1;
    int2 payload = make_int2(0, 0);
    if (e < NNZC) {
        r = rows[e];
        payload.x = cols[e];
        float v = (*flag) ? bf2f(((const ushort_t*)vals)[e]) : ((const float*)vals)[e];
        payload.y = __float_as_int(v);
    }
    for (int p = 0; p < 10; p++) {            // 150000 >> 14 = 9 max
        if ((r >> 14) == p) {
            int pos = atomicAdd(&cursor[r], 1);
            ep[pos] = payload;
        }
        __syncthreads();
    }
}

// ---- SpMM: one wave per row, lane = feature dim; fp32 end-to-end.
// readfirstlane makes row bounds scalar -> ep[] loads go down the SMEM path;
// 4-wide clamped unroll keeps 4 independent E-row gathers in flight (no serial tail).
__global__ __launch_bounds__(256) void k_spmm(const int* __restrict__ row_ptr,
                                              const int2* __restrict__ ep,
                                              const float* __restrict__ E,
                                              float* __restrict__ LE) {
    int wv = threadIdx.x >> 6;
    int r = blockIdx.x * 4 + wv;               // 37500*4 = 150000 exact
    int lane = threadIdx.x & 63;
    int s = __builtin_amdgcn_readfirstlane(row_ptr[r]);
    int e = __builtin_amdgcn_readfirstlane(row_ptr[r + 1]);
    float acc = 0.f;
    for (int i = s; i < e; i += 4) {
        int i1 = i + 1, i2 = i + 2, i3 = i + 3;
        int j1 = (i1 < e) ? i1 : s;
        int j2 = (i2 < e) ? i2 : s;
        int j3 = (i3 < e) ? i3 : s;
        int2 p0 = ep[i];
        int2 p1 = ep[j1];
        int2 p2 = ep[j2];
        int2 p3 = ep[j3];
        float w0 = __int_as_float(p0.y);
        float w1 = (i1 < e) ? __int_as_float(p1.y) : 0.f;
        float w2 = (i2 < e) ? __int_as_float(p2.y) : 0.f;
        float w3 = (i3 < e) ? __int_as_float(p3.y) : 0.f;
        float f0 = E[(size_t)p0.x * DD + lane];
        float f1 = E[(size_t)p1.x * DD + lane];
        float f2 = E[(size_t)p2.x * DD + lane];
        float f3 = E[(size_t)p3.x * DD + lane];
        acc += w0 * f0;
        acc += w1 * f1;
        acc += w2 * f2;
        acc += w3 * f3;
    }
    LE[(size_t)r * DD + lane] = acc;
}

// ---- dense (pure fp32 VALU): h = (LE+E)@W1 + (LE*E)@W2 + b1 + b2, leaky, E:=h
// One block = 16 rows (4 waves x 4 rows). Lane = (rg = lane>>4 row, cg = lane&15 -> cols cg*4..+3).
__global__ __launch_bounds__(256) void k_dense(const float* __restrict__ LE,
                                               float* __restrict__ E,
                                               const void* __restrict__ W1b,
                                               const void* __restrict__ W2b,
                                               const void* __restrict__ b1b,
                                               const void* __restrict__ b2b,
                                               const int* __restrict__ flag,
                                               int layer) {
    __shared__ __align__(16) float w1s[4096];
    __shared__ __align__(16) float w2s[4096];
    __shared__ __align__(16) float xs[4][2][4][64];   // [wave][x1|x2][rowslot][k]

    int tid  = threadIdx.x;
    int isbf = *flag;
    for (int i = tid; i < 4096; i += 256) {
        size_t off = (size_t)layer * 4096 + i;
        w1s[i] = isbf ? bf2f(((const ushort_t*)W1b)[off]) : ((const float*)W1b)[off];
        w2s[i] = isbf ? bf2f(((const ushort_t*)W2b)[off]) : ((const float*)W2b)[off];
    }

    int lane = tid & 63, wv = tid >> 6;
    int rg = lane >> 4, cg = lane & 15;

    float bsum[4];
#pragma unroll
    for (int j = 0; j < 4; j++) {
        size_t off = (size_t)layer * 64 + cg * 4 + j;
        float v1 = isbf ? bf2f(((const ushort_t*)b1b)[off]) : ((const float*)b1b)[off];
        float v2 = isbf ? bf2f(((const ushort_t*)b2b)[off]) : ((const float*)b2b)[off];
        bsum[j] = v1 + v2;
    }

    int r0 = blockIdx.x * 16 + wv * 4;     // 9375 blocks * 16 = 150000 exact

    // stage x1/x2 for 4 rows: lane covers flat elems lane*4..lane*4+3 of the 4x64 block
    const float4v* LEp = (const float4v*)(LE + (size_t)r0 * DD);
    const float4v* Ep  = (const float4v*)(E  + (size_t)r0 * DD);
    float4v l4 = LEp[lane];
    float4v e4 = Ep[lane];
    float4v x1, x2;
#pragma unroll
    for (int u = 0; u < 4; u++) { x1[u] = l4[u] + e4[u]; x2[u] = l4[u] * e4[u]; }
    int srow = lane >> 4, scol = (lane & 15) * 4;
    *(float4v*)&xs[wv][0][srow][scol] = x1;
    *(float4v*)&xs[wv][1][srow][scol] = x2;
    __syncthreads();   // also covers w1s/w2s staging

    float4v acc = {0.f, 0.f, 0.f, 0.f};
#pragma unroll
    for (int k4 = 0; k4 < 64; k4 += 4) {
        float4v x1b = *(const float4v*)&xs[wv][0][rg][k4];
        float4v x2b = *(const float4v*)&xs[wv][1][rg][k4];
#pragma unroll
        for (int u = 0; u < 4; u++) {
            float4v w1v = *(const float4v*)&w1s[(k4 + u) * 64 + cg * 4];
            float4v w2v = *(const float4v*)&w2s[(k4 + u) * 64 + cg * 4];
            acc += x1b[u] * w1v + x2b[u] * w2v;
        }
    }

    float4v st;
#pragma unroll
    for (int u = 0; u < 4; u++) {
        float h = acc[u] + bsum[u];
        st[u] = (h >= 0.f) ? h : 0.2f * h;
    }
    *(float4v*)(E + (size_t)(r0 + rg) * DD + cg * 4) = st;
}

static __device__ __forceinline__ int rid_to_node(int rid,
                                                  const int* users, const int* pos, const int* neg) {
    if (rid < BB)      return users[rid] - 1;
    if (rid < 2 * BB)  return N_USERC + pos[rid - BB] - 1;
    return N_USERC + neg[rid - 2 * BB] - 1;
}

// ---- slice 0 of output: raw initial embedding (fp32) of gathered rows ----
__global__ __launch_bounds__(256) void k_outslice0(const float* __restrict__ E,
                                                   const int* __restrict__ users,
                                                   const int* __restrict__ pos,
                                                   const int* __restrict__ neg,
                                                   float* __restrict__ out) {
    int rid  = blockIdx.x * 4 + (threadIdx.x >> 6);
    int lane = threadIdx.x & 63;
    if (rid >= NRID) return;
    int node = rid_to_node(rid, users, pos, neg);
    out[(size_t)rid * 256 + lane] = E[(size_t)node * DD + lane];
}

// ---- slice l+1: normalized current E of gathered rows (fp32) ----
__global__ __launch_bounds__(256) void k_outnorm(const float* __restrict__ E,
                                                 const int* __restrict__ users,
                                                 const int* __restrict__ pos,
                                                 const int* __restrict__ neg,
                                                 float* __restrict__ out,
                                                 int cbase) {
    int rid  = blockIdx.x * 4 + (threadIdx.x >> 6);
    int lane = threadIdx.x & 63;
    if (rid >= NRID) return;
    int node = rid_to_node(rid, users, pos, neg);
    float v = E[(size_t)node * DD + lane];
    float p2 = v * v;
    for (int m = 1; m < 64; m <<= 1) p2 += __shfl_xor(p2, m, 64);
    float nr = fmaxf(sqrtf(p2), 1e-12f);
    out[(size_t)rid * 256 + cbase + lane] = v / nr;
}

extern "C" void kernel_launch(void* const* d_in, const int* in_sizes, int n_in,
                              void* d_out, int out_size, void* d_ws, size_t ws_size,
                              hipStream_t stream) {
    const void* ue   = d_in[0];
    const void* ie   = d_in[1];
    const void* ev   = d_in[2];
    const void* W1   = d_in[3];
    const void* b1   = d_in[4];
    const void* W2   = d_in[5];
    const void* b2   = d_in[6];
    const int*  ei   = (const int*)d_in[7];
    const int*  usr  = (const int*)d_in[8];
    const int*  posi = (const int*)d_in[9];
    const int*  negi = (const int*)d_in[10];
    float*      out  = (float*)d_out;          // reference output dtype = fp32

    const int* rows = ei;
    const int* cols = ei + NNZC;

    // workspace carve — total ~98 MB
    char* w = (char*)d_ws;
    float*  E       = (float*)w;   w += (size_t)NN * DD * 4;       // 38.4 MB
    float*  LE      = (float*)w;   w += (size_t)NN * DD * 4;       // 38.4 MB
    int2*   ep      = (int2*)w;    w += (size_t)NNZC * 8;          // 19.2 MB
    int*    row_ptr = (int*)w;     w += (size_t)NBLK * 1024 * 4;   // 602112 B (doubles as tmp_ex)
    int*    cursor  = (int*)w;     w += 600064;
    int*    cnt     = (int*)w;     w += 600064;
    int*    partials= (int*)w;     w += 1024;
    int*    flag    = (int*)w;     w += 256;

    k_sniff<<<1, 64, 0, stream>>>((const unsigned int*)ue, flag);
    k_init<<<37500, 256, 0, stream>>>(ue, ie, flag, E);
    k_zero<<<586, 256, 0, stream>>>(cnt);
    k_hist<<<9375, 256, 0, stream>>>(rows, cnt);
    k_scan1<<<NBLK, 1024, 0, stream>>>(cnt, row_ptr, partials);   // row_ptr <- per-block exclusive
    k_scan2<<<1, 256, 0, stream>>>(partials);
    k_scan3<<<587, 256, 0, stream>>>(row_ptr, partials, cursor);
    k_scatter<<<9375, 256, 0, stream>>>(rows, cols, ev, flag, cursor, ep);

    k_outslice0<<<3072, 256, 0, stream>>>(E, usr, posi, negi, out);

    for (int l = 0; l < NLAYER; l++) {
        k_spmm<<<37500, 256, 0, stream>>>(row_ptr, ep, E, LE);
        k_dense<<<9375, 256, 0, stream>>>(LE, E, W1, W2, b1, b2, flag, l);
        k_outnorm<<<3072, 256, 0, stream>>>(E, usr, posi, negi, out, 64 * (l + 1));
    }
}

// Round 7
// 719.677 us; speedup vs baseline: 1.8824x; 1.3115x over previous
//
#include <hip/hip_runtime.h>

#define N_USERC 50000
#define N_ITEMC 100000
#define NN      150000      // total nodes
#define DD      64
#define NLAYER  3
#define NNZC    2400000
#define BB      4096
#define NRID    (3*BB)      // 12288 gathered output rows
#define NBKT    147         // ceil(NN/1024) row buckets (row>>10)
#define NABLK   586         // ceil(NNZC/4096) partition blocks

typedef unsigned short ushort_t;

static __device__ __forceinline__ float bf2f(ushort_t b) {
    unsigned int u = ((unsigned int)b) << 16;
    return __uint_as_float(u);
}
static __device__ __forceinline__ float rlane(float x, int k) {
    return __int_as_float(__builtin_amdgcn_readlane(__float_as_int(x), k));
}

// ---- dtype sniff: flag=1 if float inputs are packed bf16, 0 if fp32 ----
__global__ __launch_bounds__(64) void k_sniff(const unsigned int* __restrict__ ue_words,
                                              int* __restrict__ flag) {
    int lane = threadIdx.x;
    int cnt = 0;
    for (int i = 0; i < 4; i++) {
        unsigned int w = ue_words[lane * 4 + i];
        unsigned int lo = w & 0xFFFFu;
        unsigned int ex = (lo >> 7) & 0xFF;
        if (ex >= 100 && ex <= 132) cnt++;
    }
    for (int m = 1; m < 64; m <<= 1) cnt += __shfl_xor(cnt, m, 64);
    if (lane == 0) *flag = (cnt >= 128) ? 1 : 0;
}

// ---- init: E fp32 from inputs ----
__global__ __launch_bounds__(256) void k_init(const void* __restrict__ ue,
                                              const void* __restrict__ ie,
                                              const int* __restrict__ flag,
                                              float* __restrict__ E) {
    int idx = blockIdx.x * 256 + threadIdx.x;           // over NN*64
    if (idx >= NN * DD) return;
    int row = idx >> 6;
    bool isU = row < N_USERC;
    int si = isU ? idx : idx - N_USERC * DD;
    float v;
    if (*flag) {
        v = bf2f(isU ? ((const ushort_t*)ue)[si] : ((const ushort_t*)ie)[si]);
    } else {
        v = isU ? ((const float*)ue)[si] : ((const float*)ie)[si];
    }
    E[idx] = v;
}

// ---- zero the 147 bucket counters ----
__global__ __launch_bounds__(256) void k_zb(int* __restrict__ bucket_cnt) {
    if (threadIdx.x < NBKT) bucket_cnt[threadIdx.x] = 0;
}

// ---- bucket histogram: 147 buckets of 1024 rows ----
__global__ __launch_bounds__(256) void k_bhist(const int* __restrict__ rows,
                                               int* __restrict__ bucket_cnt) {
    __shared__ int h[NBKT];
    int t = threadIdx.x;
    if (t < NBKT) h[t] = 0;
    __syncthreads();
    int e0 = blockIdx.x * 4096;
#pragma unroll
    for (int i = 0; i < 16; i++) {
        int e = e0 + t + i * 256;
        if (e < NNZC) atomicAdd(&h[rows[e] >> 10], 1);
    }
    __syncthreads();
    if (t < NBKT && h[t]) atomicAdd(&bucket_cnt[t], h[t]);
}

// ---- exclusive scan of 147 bucket counts; seed bases/cursors ----
__global__ __launch_bounds__(256) void k_bscan(const int* __restrict__ bucket_cnt,
                                               int* __restrict__ gbase,
                                               int* __restrict__ gcursor,
                                               int* __restrict__ row_ptr) {
    __shared__ int s[256];
    int t = threadIdx.x;
    int v = (t < NBKT) ? bucket_cnt[t] : 0;
    s[t] = v; __syncthreads();
    for (int off = 1; off < 256; off <<= 1) {
        int x = (t >= off) ? s[t - off] : 0;
        __syncthreads();
        s[t] += x;
        __syncthreads();
    }
    if (t < NBKT) { int ex = s[t] - v; gbase[t] = ex; gcursor[t] = ex; }
    if (t == 0) { gbase[NBKT] = NNZC; row_ptr[NN] = NNZC; }
}

// ---- phase A: partition edges into 147 row-buckets. Per-block contiguous runs
// (avg 28 edges = 223 B) from a single block -> lines merge in that XCD's L2.
// Only 86K global atomics (one per block x non-empty bucket). ----
__global__ __launch_bounds__(256) void k_phaseA(const int* __restrict__ rows,
                                                const int* __restrict__ cols,
                                                const void* __restrict__ vals,
                                                const int* __restrict__ flag,
                                                int* __restrict__ gcursor,
                                                int2* __restrict__ binned) {
    __shared__ int hist[NBKT], base_[NBKT], lcur[NBKT];
    int t = threadIdx.x;
    int e0 = blockIdx.x * 4096;
    if (t < NBKT) { hist[t] = 0; lcur[t] = 0; }
    __syncthreads();
    int myrow[16];
#pragma unroll
    for (int i = 0; i < 16; i++) {
        int e = e0 + t + i * 256;
        int r = -1;
        if (e < NNZC) { r = rows[e]; atomicAdd(&hist[r >> 10], 1); }
        myrow[i] = r;
    }
    __syncthreads();
    if (t < NBKT && hist[t] > 0) base_[t] = atomicAdd(&gcursor[t], hist[t]);
    __syncthreads();
    int isbf = *flag;
#pragma unroll
    for (int i = 0; i < 16; i++) {
        int e = e0 + t + i * 256;
        if (e < NNZC) {
            int r = myrow[i];
            int bkt = r >> 10;
            int off = atomicAdd(&lcur[bkt], 1);
            int pos = base_[bkt] + off;
            int c = cols[e];
            float v = isbf ? bf2f(((const ushort_t*)vals)[e]) : ((const float*)vals)[e];
            // pack: row_local(10b) << 18 | col(18b); val bits separate
            binned[pos] = make_int2(((r & 1023) << 18) | c, __float_as_int(v));
        }
    }
}

// ---- phase B: one block per bucket. Exact CSR slice via LDS hist+scan+cursor;
// all writes block-private & region-confined -> full-line evictions. ----
__global__ __launch_bounds__(256) void k_phaseB(const int* __restrict__ gbase,
                                                const int2* __restrict__ binned,
                                                int2* __restrict__ ep,
                                                int* __restrict__ row_ptr) {
    __shared__ int rc[1024];    // counts -> inclusive scan
    __shared__ int rofs[1024];  // counts copy -> exclusive -> cursor
    int b = blockIdx.x, t = threadIdx.x;
    int s = gbase[b], e = gbase[b + 1];
    for (int i = t; i < 1024; i += 256) rc[i] = 0;
    __syncthreads();
    for (int i = s + t; i < e; i += 256)
        atomicAdd(&rc[binned[i].x >> 18], 1);
    __syncthreads();
    for (int i = t; i < 1024; i += 256) rofs[i] = rc[i];
    __syncthreads();
    for (int off = 1; off < 1024; off <<= 1) {
        int v[4];
#pragma unroll
        for (int j = 0; j < 4; j++) {
            int idx = t + j * 256;
            v[j] = (idx >= off) ? rc[idx - off] : 0;
        }
        __syncthreads();
#pragma unroll
        for (int j = 0; j < 4; j++) rc[t + j * 256] += v[j];
        __syncthreads();
    }
    for (int i = t; i < 1024; i += 256) {
        int ex = rc[i] - rofs[i];          // exclusive
        int gr = b * 1024 + i;
        if (gr < NN) row_ptr[gr] = s + ex;
        rofs[i] = ex;                      // becomes cursor
    }
    __syncthreads();
    for (int i = s + t; i < e; i += 256) {
        int2 en = binned[i];
        int rl = en.x >> 18;
        int c  = en.x & 0x3FFFF;
        int off = atomicAdd(&rofs[rl], 1);
        ep[s + off] = make_int2(c, en.y);
    }
}

// ---- SpMM: unchanged from round 5 (control) ----
__global__ __launch_bounds__(256) void k_spmm(const int* __restrict__ row_ptr,
                                              const int2* __restrict__ ep,
                                              const float* __restrict__ E,
                                              float* __restrict__ LE) {
    int wv = threadIdx.x >> 6;
    int r = blockIdx.x * 4 + wv;               // 37500*4 = 150000 exact
    int lane = threadIdx.x & 63;
    int s = __builtin_amdgcn_readfirstlane(row_ptr[r]);
    int e = __builtin_amdgcn_readfirstlane(row_ptr[r + 1]);
    float acc = 0.f;
    for (int i = s; i < e; i += 4) {
        int i1 = i + 1, i2 = i + 2, i3 = i + 3;
        int j1 = (i1 < e) ? i1 : s;
        int j2 = (i2 < e) ? i2 : s;
        int j3 = (i3 < e) ? i3 : s;
        int2 p0 = ep[i];
        int2 p1 = ep[j1];
        int2 p2 = ep[j2];
        int2 p3 = ep[j3];
        float w0 = __int_as_float(p0.y);
        float w1 = (i1 < e) ? __int_as_float(p1.y) : 0.f;
        float w2 = (i2 < e) ? __int_as_float(p2.y) : 0.f;
        float w3 = (i3 < e) ? __int_as_float(p3.y) : 0.f;
        float f0 = E[(size_t)p0.x * DD + lane];
        float f1 = E[(size_t)p1.x * DD + lane];
        float f2 = E[(size_t)p2.x * DD + lane];
        float f3 = E[(size_t)p3.x * DD + lane];
        acc += w0 * f0;
        acc += w1 * f1;
        acc += w2 * f2;
        acc += w3 * f3;
    }
    LE[(size_t)r * DD + lane] = acc;
}

// ---- dense v2: lane = col; W1/W2 columns in 128 VGPRs; x broadcast via
// v_readlane (constant k) into v_fmac. No LDS. 2 rows x 2 split-k accs = 4
// independent FMA chains. h = (LE+E)@W1 + (LE*E)@W2 + b1+b2, leaky, E := h. ----
__global__ __launch_bounds__(256) void k_dense2(const float* __restrict__ LE,
                                                float* __restrict__ E,
                                                const void* __restrict__ W1b,
                                                const void* __restrict__ W2b,
                                                const void* __restrict__ b1b,
                                                const void* __restrict__ b2b,
                                                const int* __restrict__ flag,
                                                int layer) {
    int lane = threadIdx.x & 63;
    int gw = (blockIdx.x * 256 + threadIdx.x) >> 6;
    int nw = (gridDim.x * 256) >> 6;
    int isbf = *flag;

    float w1r[64], w2r[64];
    size_t Wo = (size_t)layer * 4096 + lane;
#pragma unroll
    for (int k = 0; k < 64; k++) {
        w1r[k] = isbf ? bf2f(((const ushort_t*)W1b)[Wo + (size_t)k * 64])
                      : ((const float*)W1b)[Wo + (size_t)k * 64];
        w2r[k] = isbf ? bf2f(((const ushort_t*)W2b)[Wo + (size_t)k * 64])
                      : ((const float*)W2b)[Wo + (size_t)k * 64];
    }
    size_t bo = (size_t)layer * 64 + lane;
    float bias = (isbf ? bf2f(((const ushort_t*)b1b)[bo]) : ((const float*)b1b)[bo])
               + (isbf ? bf2f(((const ushort_t*)b2b)[bo]) : ((const float*)b2b)[bo]);

    for (int r0 = gw * 2; r0 < NN; r0 += nw * 2) {
        const float* LA = LE + (size_t)r0 * DD;
        float*       EA = E  + (size_t)r0 * DD;
        float leA = LA[lane],      eA = EA[lane];
        float leB = LA[DD + lane], eB = EA[DD + lane];
        float x1A = leA + eA, x2A = leA * eA;
        float x1B = leB + eB, x2B = leB * eB;
        float a0 = 0.f, a1 = 0.f, c0 = 0.f, c1 = 0.f;
#pragma unroll
        for (int k = 0; k < 64; k += 2) {
            a0 = fmaf(rlane(x1A, k),     w1r[k],     a0);
            a0 = fmaf(rlane(x2A, k),     w2r[k],     a0);
            a1 = fmaf(rlane(x1A, k + 1), w1r[k + 1], a1);
            a1 = fmaf(rlane(x2A, k + 1), w2r[k + 1], a1);
            c0 = fmaf(rlane(x1B, k),     w1r[k],     c0);
            c0 = fmaf(rlane(x2B, k),     w2r[k],     c0);
            c1 = fmaf(rlane(x1B, k + 1), w1r[k + 1], c1);
            c1 = fmaf(rlane(x2B, k + 1), w2r[k + 1], c1);
        }
        float hA = a0 + a1 + bias; hA = (hA >= 0.f) ? hA : 0.2f * hA;
        float hB = c0 + c1 + bias; hB = (hB >= 0.f) ? hB : 0.2f * hB;
        EA[lane] = hA;
        EA[DD + lane] = hB;
    }
}

static __device__ __forceinline__ int rid_to_node(int rid,
                                                  const int* users, const int* pos, const int* neg) {
    if (rid < BB)      return users[rid] - 1;
    if (rid < 2 * BB)  return N_USERC + pos[rid - BB] - 1;
    return N_USERC + neg[rid - 2 * BB] - 1;
}

// ---- slice 0 of output: raw initial embedding (fp32) of gathered rows ----
__global__ __launch_bounds__(256) void k_outslice0(const float* __restrict__ E,
                                                   const int* __restrict__ users,
                                                   const int* __restrict__ pos,
                                                   const int* __restrict__ neg,
                                                   float* __restrict__ out) {
    int rid  = blockIdx.x * 4 + (threadIdx.x >> 6);
    int lane = threadIdx.x & 63;
    if (rid >= NRID) return;
    int node = rid_to_node(rid, users, pos, neg);
    out[(size_t)rid * 256 + lane] = E[(size_t)node * DD + lane];
}

// ---- slice l+1: normalized current E of gathered rows (fp32) ----
__global__ __launch_bounds__(256) void k_outnorm(const float* __restrict__ E,
                                                 const int* __restrict__ users,
                                                 const int* __restrict__ pos,
                                                 const int* __restrict__ neg,
                                                 float* __restrict__ out,
                                                 int cbase) {
    int rid  = blockIdx.x * 4 + (threadIdx.x >> 6);
    int lane = threadIdx.x & 63;
    if (rid >= NRID) return;
    int node = rid_to_node(rid, users, pos, neg);
    float v = E[(size_t)node * DD + lane];
    float p2 = v * v;
    for (int m = 1; m < 64; m <<= 1) p2 += __shfl_xor(p2, m, 64);
    float nr = fmaxf(sqrtf(p2), 1e-12f);
    out[(size_t)rid * 256 + cbase + lane] = v / nr;
}

extern "C" void kernel_launch(void* const* d_in, const int* in_sizes, int n_in,
                              void* d_out, int out_size, void* d_ws, size_t ws_size,
                              hipStream_t stream) {
    const void* ue   = d_in[0];
    const void* ie   = d_in[1];
    const void* ev   = d_in[2];
    const void* W1   = d_in[3];
    const void* b1   = d_in[4];
    const void* W2   = d_in[5];
    const void* b2   = d_in[6];
    const int*  ei   = (const int*)d_in[7];
    const int*  usr  = (const int*)d_in[8];
    const int*  posi = (const int*)d_in[9];
    const int*  negi = (const int*)d_in[10];
    float*      out  = (float*)d_out;          // reference output dtype = fp32

    const int* rows = ei;
    const int* cols = ei + NNZC;

    // workspace carve — total ~116 MB
    char* w = (char*)d_ws;
    float*  E         = (float*)w;  w += (size_t)NN * DD * 4;    // 38.4 MB
    float*  LE        = (float*)w;  w += (size_t)NN * DD * 4;    // 38.4 MB
    int2*   binned    = (int2*)w;   w += (size_t)NNZC * 8;       // 19.2 MB
    int2*   ep        = (int2*)w;   w += (size_t)NNZC * 8;       // 19.2 MB
    int*    row_ptr   = (int*)w;    w += 600320;                 // NN+1 ints padded
    int*    gbase     = (int*)w;    w += 1024;                   // NBKT+1
    int*    gcursor   = (int*)w;    w += 1024;
    int*    bucket_cnt= (int*)w;    w += 1024;
    int*    flag      = (int*)w;    w += 256;

    k_sniff<<<1, 64, 0, stream>>>((const unsigned int*)ue, flag);
    k_init<<<37500, 256, 0, stream>>>(ue, ie, flag, E);
    k_zb<<<1, 256, 0, stream>>>(bucket_cnt);
    k_bhist<<<NABLK, 256, 0, stream>>>(rows, bucket_cnt);
    k_bscan<<<1, 256, 0, stream>>>(bucket_cnt, gbase, gcursor, row_ptr);
    k_phaseA<<<NABLK, 256, 0, stream>>>(rows, cols, ev, flag, gcursor, binned);
    k_phaseB<<<NBKT, 256, 0, stream>>>(gbase, binned, ep, row_ptr);

    k_outslice0<<<3072, 256, 0, stream>>>(E, usr, posi, negi, out);

    for (int l = 0; l < NLAYER; l++) {
        k_spmm<<<37500, 256, 0, stream>>>(row_ptr, ep, E, LE);
        k_dense2<<<768, 256, 0, stream>>>(LE, E, W1, W2, b1, b2, flag, l);
        k_outnorm<<<3072, 256, 0, stream>>>(E, usr, posi, negi, out, 64 * (l + 1));
    }
}

// Round 8
// 714.024 us; speedup vs baseline: 1.8973x; 1.0079x over previous
//
#include <hip/hip_runtime.h>

#define N_USERC 50000
#define N_ITEMC 100000
#define NN      150000      // total nodes
#define DD      64
#define NLAYER  3
#define NNZC    2400000
#define BB      4096
#define NRID    (3*BB)      // 12288 gathered output rows
#define NBKT    147         // ceil(NN/1024) row buckets (row>>10)
#define NABLK   586         // ceil(NNZC/4096) partition blocks

typedef unsigned short ushort_t;

static __device__ __forceinline__ float bf2f(ushort_t b) {
    unsigned int u = ((unsigned int)b) << 16;
    return __uint_as_float(u);
}
static __device__ __forceinline__ ushort_t f2bf(float f) {
    unsigned int u = __float_as_uint(f);
    u = u + 0x7FFFu + ((u >> 16) & 1u);   // round-to-nearest-even
    return (ushort_t)(u >> 16);
}
static __device__ __forceinline__ float rlane(float x, int k) {
    return __int_as_float(__builtin_amdgcn_readlane(__float_as_int(x), k));
}

// ---- dtype sniff: flag=1 if float inputs are packed bf16, 0 if fp32 ----
__global__ __launch_bounds__(64) void k_sniff(const unsigned int* __restrict__ ue_words,
                                              int* __restrict__ flag) {
    int lane = threadIdx.x;
    int cnt = 0;
    for (int i = 0; i < 4; i++) {
        unsigned int w = ue_words[lane * 4 + i];
        unsigned int lo = w & 0xFFFFu;
        unsigned int ex = (lo >> 7) & 0xFF;
        if (ex >= 100 && ex <= 132) cnt++;
    }
    for (int m = 1; m < 64; m <<= 1) cnt += __shfl_xor(cnt, m, 64);
    if (lane == 0) *flag = (cnt >= 128) ? 1 : 0;
}

// ---- init: E fp32 from inputs ----
__global__ __launch_bounds__(256) void k_init(const void* __restrict__ ue,
                                              const void* __restrict__ ie,
                                              const int* __restrict__ flag,
                                              float* __restrict__ E) {
    int idx = blockIdx.x * 256 + threadIdx.x;           // over NN*64
    if (idx >= NN * DD) return;
    int row = idx >> 6;
    bool isU = row < N_USERC;
    int si = isU ? idx : idx - N_USERC * DD;
    float v;
    if (*flag) {
        v = bf2f(isU ? ((const ushort_t*)ue)[si] : ((const ushort_t*)ie)[si]);
    } else {
        v = isU ? ((const float*)ue)[si] : ((const float*)ie)[si];
    }
    E[idx] = v;
}

// ---- E (fp32) -> Eb (bf16 gather copy); runs after phaseB (Eb aliases binned) ----
__global__ __launch_bounds__(256) void k_tobf(const float* __restrict__ E,
                                              ushort_t* __restrict__ Eb) {
    int idx = blockIdx.x * 256 + threadIdx.x;
    if (idx < NN * DD) Eb[idx] = f2bf(E[idx]);
}

// ---- zero the 147 bucket counters ----
__global__ __launch_bounds__(256) void k_zb(int* __restrict__ bucket_cnt) {
    if (threadIdx.x < NBKT) bucket_cnt[threadIdx.x] = 0;
}

// ---- bucket histogram: 147 buckets of 1024 rows ----
__global__ __launch_bounds__(256) void k_bhist(const int* __restrict__ rows,
                                               int* __restrict__ bucket_cnt) {
    __shared__ int h[NBKT];
    int t = threadIdx.x;
    if (t < NBKT) h[t] = 0;
    __syncthreads();
    int e0 = blockIdx.x * 4096;
#pragma unroll
    for (int i = 0; i < 16; i++) {
        int e = e0 + t + i * 256;
        if (e < NNZC) atomicAdd(&h[rows[e] >> 10], 1);
    }
    __syncthreads();
    if (t < NBKT && h[t]) atomicAdd(&bucket_cnt[t], h[t]);
}

// ---- exclusive scan of 147 bucket counts; seed bases/cursors ----
__global__ __launch_bounds__(256) void k_bscan(const int* __restrict__ bucket_cnt,
                                               int* __restrict__ gbase,
                                               int* __restrict__ gcursor,
                                               int* __restrict__ row_ptr) {
    __shared__ int s[256];
    int t = threadIdx.x;
    int v = (t < NBKT) ? bucket_cnt[t] : 0;
    s[t] = v; __syncthreads();
    for (int off = 1; off < 256; off <<= 1) {
        int x = (t >= off) ? s[t - off] : 0;
        __syncthreads();
        s[t] += x;
        __syncthreads();
    }
    if (t < NBKT) { int ex = s[t] - v; gbase[t] = ex; gcursor[t] = ex; }
    if (t == 0) { gbase[NBKT] = NNZC; row_ptr[NN] = NNZC; }
}

// ---- phase A: partition edges into 147 row-buckets ----
__global__ __launch_bounds__(256) void k_phaseA(const int* __restrict__ rows,
                                                const int* __restrict__ cols,
                                                const void* __restrict__ vals,
                                                const int* __restrict__ flag,
                                                int* __restrict__ gcursor,
                                                int2* __restrict__ binned) {
    __shared__ int hist[NBKT], base_[NBKT], lcur[NBKT];
    int t = threadIdx.x;
    int e0 = blockIdx.x * 4096;
    if (t < NBKT) { hist[t] = 0; lcur[t] = 0; }
    __syncthreads();
    int myrow[16];
#pragma unroll
    for (int i = 0; i < 16; i++) {
        int e = e0 + t + i * 256;
        int r = -1;
        if (e < NNZC) { r = rows[e]; atomicAdd(&hist[r >> 10], 1); }
        myrow[i] = r;
    }
    __syncthreads();
    if (t < NBKT && hist[t] > 0) base_[t] = atomicAdd(&gcursor[t], hist[t]);
    __syncthreads();
    int isbf = *flag;
#pragma unroll
    for (int i = 0; i < 16; i++) {
        int e = e0 + t + i * 256;
        if (e < NNZC) {
            int r = myrow[i];
            int bkt = r >> 10;
            int off = atomicAdd(&lcur[bkt], 1);
            int pos = base_[bkt] + off;
            int c = cols[e];
            float v = isbf ? bf2f(((const ushort_t*)vals)[e]) : ((const float*)vals)[e];
            // pack: row_local(10b) << 18 | col(18b); val bits separate
            binned[pos] = make_int2(((r & 1023) << 18) | c, __float_as_int(v));
        }
    }
}

// ---- phase B: one block per bucket; exact CSR slice via LDS hist+scan+cursor ----
__global__ __launch_bounds__(256) void k_phaseB(const int* __restrict__ gbase,
                                                const int2* __restrict__ binned,
                                                int2* __restrict__ ep,
                                                int* __restrict__ row_ptr) {
    __shared__ int rc[1024];    // counts -> inclusive scan
    __shared__ int rofs[1024];  // counts copy -> exclusive -> cursor
    int b = blockIdx.x, t = threadIdx.x;
    int s = gbase[b], e = gbase[b + 1];
    for (int i = t; i < 1024; i += 256) rc[i] = 0;
    __syncthreads();
    for (int i = s + t; i < e; i += 256)
        atomicAdd(&rc[binned[i].x >> 18], 1);
    __syncthreads();
    for (int i = t; i < 1024; i += 256) rofs[i] = rc[i];
    __syncthreads();
    for (int off = 1; off < 1024; off <<= 1) {
        int v[4];
#pragma unroll
        for (int j = 0; j < 4; j++) {
            int idx = t + j * 256;
            v[j] = (idx >= off) ? rc[idx - off] : 0;
        }
        __syncthreads();
#pragma unroll
        for (int j = 0; j < 4; j++) rc[t + j * 256] += v[j];
        __syncthreads();
    }
    for (int i = t; i < 1024; i += 256) {
        int ex = rc[i] - rofs[i];          // exclusive
        int gr = b * 1024 + i;
        if (gr < NN) row_ptr[gr] = s + ex;
        rofs[i] = ex;                      // becomes cursor
    }
    __syncthreads();
    for (int i = s + t; i < e; i += 256) {
        int2 en = binned[i];
        int rl = en.x >> 18;
        int c  = en.x & 0x3FFFF;
        int off = atomicAdd(&rofs[rl], 1);
        ep[s + off] = make_int2(c, en.y);
    }
}

// ---- SpMM: one wave per row; gathers from bf16 Eb (128 B/edge vs 256) ----
__global__ __launch_bounds__(256) void k_spmm(const int* __restrict__ row_ptr,
                                              const int2* __restrict__ ep,
                                              const ushort_t* __restrict__ Eb,
                                              float* __restrict__ LE) {
    int wv = threadIdx.x >> 6;
    int r = blockIdx.x * 4 + wv;               // 37500*4 = 150000 exact
    int lane = threadIdx.x & 63;
    int s = __builtin_amdgcn_readfirstlane(row_ptr[r]);
    int e = __builtin_amdgcn_readfirstlane(row_ptr[r + 1]);
    float acc = 0.f;
    for (int i = s; i < e; i += 4) {
        int i1 = i + 1, i2 = i + 2, i3 = i + 3;
        int j1 = (i1 < e) ? i1 : s;
        int j2 = (i2 < e) ? i2 : s;
        int j3 = (i3 < e) ? i3 : s;
        int2 p0 = ep[i];
        int2 p1 = ep[j1];
        int2 p2 = ep[j2];
        int2 p3 = ep[j3];
        float w0 = __int_as_float(p0.y);
        float w1 = (i1 < e) ? __int_as_float(p1.y) : 0.f;
        float w2 = (i2 < e) ? __int_as_float(p2.y) : 0.f;
        float w3 = (i3 < e) ? __int_as_float(p3.y) : 0.f;
        float f0 = bf2f(Eb[(size_t)p0.x * DD + lane]);
        float f1 = bf2f(Eb[(size_t)p1.x * DD + lane]);
        float f2 = bf2f(Eb[(size_t)p2.x * DD + lane]);
        float f3 = bf2f(Eb[(size_t)p3.x * DD + lane]);
        acc += w0 * f0;
        acc += w1 * f1;
        acc += w2 * f2;
        acc += w3 * f3;
    }
    LE[(size_t)r * DD + lane] = acc;
}

// ---- dense v2: lane = col; W columns in VGPRs; x broadcast via v_readlane.
// Updates both E (fp32, truth) and Eb (bf16 gather copy). ----
__global__ __launch_bounds__(256) void k_dense2(const float* __restrict__ LE,
                                                float* __restrict__ E,
                                                ushort_t* __restrict__ Eb,
                                                const void* __restrict__ W1b,
                                                const void* __restrict__ W2b,
                                                const void* __restrict__ b1b,
                                                const void* __restrict__ b2b,
                                                const int* __restrict__ flag,
                                                int layer) {
    int lane = threadIdx.x & 63;
    int gw = (blockIdx.x * 256 + threadIdx.x) >> 6;
    int nw = (gridDim.x * 256) >> 6;
    int isbf = *flag;

    float w1r[64], w2r[64];
    size_t Wo = (size_t)layer * 4096 + lane;
#pragma unroll
    for (int k = 0; k < 64; k++) {
        w1r[k] = isbf ? bf2f(((const ushort_t*)W1b)[Wo + (size_t)k * 64])
                      : ((const float*)W1b)[Wo + (size_t)k * 64];
        w2r[k] = isbf ? bf2f(((const ushort_t*)W2b)[Wo + (size_t)k * 64])
                      : ((const float*)W2b)[Wo + (size_t)k * 64];
    }
    size_t bo = (size_t)layer * 64 + lane;
    float bias = (isbf ? bf2f(((const ushort_t*)b1b)[bo]) : ((const float*)b1b)[bo])
               + (isbf ? bf2f(((const ushort_t*)b2b)[bo]) : ((const float*)b2b)[bo]);

    for (int r0 = gw * 2; r0 < NN; r0 += nw * 2) {
        const float* LA = LE + (size_t)r0 * DD;
        float*       EA = E  + (size_t)r0 * DD;
        float leA = LA[lane],      eA = EA[lane];
        float leB = LA[DD + lane], eB = EA[DD + lane];
        float x1A = leA + eA, x2A = leA * eA;
        float x1B = leB + eB, x2B = leB * eB;
        float a0 = 0.f, a1 = 0.f, c0 = 0.f, c1 = 0.f;
#pragma unroll
        for (int k = 0; k < 64; k += 2) {
            a0 = fmaf(rlane(x1A, k),     w1r[k],     a0);
            a0 = fmaf(rlane(x2A, k),     w2r[k],     a0);
            a1 = fmaf(rlane(x1A, k + 1), w1r[k + 1], a1);
            a1 = fmaf(rlane(x2A, k + 1), w2r[k + 1], a1);
            c0 = fmaf(rlane(x1B, k),     w1r[k],     c0);
            c0 = fmaf(rlane(x2B, k),     w2r[k],     c0);
            c1 = fmaf(rlane(x1B, k + 1), w1r[k + 1], c1);
            c1 = fmaf(rlane(x2B, k + 1), w2r[k + 1], c1);
        }
        float hA = a0 + a1 + bias; hA = (hA >= 0.f) ? hA : 0.2f * hA;
        float hB = c0 + c1 + bias; hB = (hB >= 0.f) ? hB : 0.2f * hB;
        EA[lane] = hA;
        EA[DD + lane] = hB;
        Eb[(size_t)r0 * DD + lane] = f2bf(hA);
        Eb[(size_t)r0 * DD + DD + lane] = f2bf(hB);
    }
}

static __device__ __forceinline__ int rid_to_node(int rid,
                                                  const int* users, const int* pos, const int* neg) {
    if (rid < BB)      return users[rid] - 1;
    if (rid < 2 * BB)  return N_USERC + pos[rid - BB] - 1;
    return N_USERC + neg[rid - 2 * BB] - 1;
}

// ---- slice 0 of output: raw initial embedding (fp32) of gathered rows ----
__global__ __launch_bounds__(256) void k_outslice0(const float* __restrict__ E,
                                                   const int* __restrict__ users,
                                                   const int* __restrict__ pos,
                                                   const int* __restrict__ neg,
                                                   float* __restrict__ out) {
    int rid  = blockIdx.x * 4 + (threadIdx.x >> 6);
    int lane = threadIdx.x & 63;
    if (rid >= NRID) return;
    int node = rid_to_node(rid, users, pos, neg);
    out[(size_t)rid * 256 + lane] = E[(size_t)node * DD + lane];
}

// ---- slice l+1: normalized current E of gathered rows (fp32) ----
__global__ __launch_bounds__(256) void k_outnorm(const float* __restrict__ E,
                                                 const int* __restrict__ users,
                                                 const int* __restrict__ pos,
                                                 const int* __restrict__ neg,
                                                 float* __restrict__ out,
                                                 int cbase) {
    int rid  = blockIdx.x * 4 + (threadIdx.x >> 6);
    int lane = threadIdx.x & 63;
    if (rid >= NRID) return;
    int node = rid_to_node(rid, users, pos, neg);
    float v = E[(size_t)node * DD + lane];
    float p2 = v * v;
    for (int m = 1; m < 64; m <<= 1) p2 += __shfl_xor(p2, m, 64);
    float nr = fmaxf(sqrtf(p2), 1e-12f);
    out[(size_t)rid * 256 + cbase + lane] = v / nr;
}

extern "C" void kernel_launch(void* const* d_in, const int* in_sizes, int n_in,
                              void* d_out, int out_size, void* d_ws, size_t ws_size,
                              hipStream_t stream) {
    const void* ue   = d_in[0];
    const void* ie   = d_in[1];
    const void* ev   = d_in[2];
    const void* W1   = d_in[3];
    const void* b1   = d_in[4];
    const void* W2   = d_in[5];
    const void* b2   = d_in[6];
    const int*  ei   = (const int*)d_in[7];
    const int*  usr  = (const int*)d_in[8];
    const int*  posi = (const int*)d_in[9];
    const int*  negi = (const int*)d_in[10];
    float*      out  = (float*)d_out;          // reference output dtype = fp32

    const int* rows = ei;
    const int* cols = ei + NNZC;

    // workspace carve — total ~116 MB (Eb aliases binned: binned is dead after phaseB)
    char* w = (char*)d_ws;
    float*  E         = (float*)w;  w += (size_t)NN * DD * 4;    // 38.4 MB
    float*  LE        = (float*)w;  w += (size_t)NN * DD * 4;    // 38.4 MB
    int2*   binned    = (int2*)w;   w += (size_t)NNZC * 8;       // 19.2 MB
    ushort_t* Eb      = (ushort_t*)binned;                       // alias (19.2 MB need)
    int2*   ep        = (int2*)w;   w += (size_t)NNZC * 8;       // 19.2 MB
    int*    row_ptr   = (int*)w;    w += 600320;                 // NN+1 ints padded
    int*    gbase     = (int*)w;    w += 1024;                   // NBKT+1
    int*    gcursor   = (int*)w;    w += 1024;
    int*    bucket_cnt= (int*)w;    w += 1024;
    int*    flag      = (int*)w;    w += 256;

    k_sniff<<<1, 64, 0, stream>>>((const unsigned int*)ue, flag);
    k_init<<<37500, 256, 0, stream>>>(ue, ie, flag, E);
    k_zb<<<1, 256, 0, stream>>>(bucket_cnt);
    k_bhist<<<NABLK, 256, 0, stream>>>(rows, bucket_cnt);
    k_bscan<<<1, 256, 0, stream>>>(bucket_cnt, gbase, gcursor, row_ptr);
    k_phaseA<<<NABLK, 256, 0, stream>>>(rows, cols, ev, flag, gcursor, binned);
    k_phaseB<<<NBKT, 256, 0, stream>>>(gbase, binned, ep, row_ptr);
    k_tobf<<<37500, 256, 0, stream>>>(E, Eb);      // after phaseB: binned is dead

    k_outslice0<<<3072, 256, 0, stream>>>(E, usr, posi, negi, out);

    for (int l = 0; l < NLAYER; l++) {
        k_spmm<<<37500, 256, 0, stream>>>(row_ptr, ep, Eb, LE);
        k_dense2<<<768, 256, 0, stream>>>(LE, E, Eb, W1, W2, b1, b2, flag, l);
        k_outnorm<<<3072, 256, 0, stream>>>(E, usr, posi, negi, out, 64 * (l + 1));
    }
}

// Round 9
// 657.912 us; speedup vs baseline: 2.0592x; 1.0853x over previous
//
#include <hip/hip_runtime.h>

#define N_USERC 50000
#define N_ITEMC 100000
#define NN      150000      // total nodes
#define DD      64
#define NLAYER  3
#define NNZC    2400000
#define BB      4096
#define NRID    (3*BB)      // 12288 gathered output rows
#define NBKT    147         // ceil(NN/1024) row buckets (row>>10)
#define NABLK   586         // ceil(NNZC/4096) partition blocks

typedef unsigned short ushort_t;

static __device__ __forceinline__ float bf2f(ushort_t b) {
    unsigned int u = ((unsigned int)b) << 16;
    return __uint_as_float(u);
}
static __device__ __forceinline__ ushort_t f2bf(float f) {
    unsigned int u = __float_as_uint(f);
    u = u + 0x7FFFu + ((u >> 16) & 1u);   // round-to-nearest-even
    return (ushort_t)(u >> 16);
}
static __device__ __forceinline__ float rlane(float x, int k) {
    return __int_as_float(__builtin_amdgcn_readlane(__float_as_int(x), k));
}

// ---- dtype sniff: flag=1 if float inputs are packed bf16, 0 if fp32 ----
__global__ __launch_bounds__(64) void k_sniff(const unsigned int* __restrict__ ue_words,
                                              int* __restrict__ flag) {
    int lane = threadIdx.x;
    int cnt = 0;
    for (int i = 0; i < 4; i++) {
        unsigned int w = ue_words[lane * 4 + i];
        unsigned int lo = w & 0xFFFFu;
        unsigned int ex = (lo >> 7) & 0xFF;
        if (ex >= 100 && ex <= 132) cnt++;
    }
    for (int m = 1; m < 64; m <<= 1) cnt += __shfl_xor(cnt, m, 64);
    if (lane == 0) *flag = (cnt >= 128) ? 1 : 0;
}

// ---- init: E fp32 from inputs ----
__global__ __launch_bounds__(256) void k_init(const void* __restrict__ ue,
                                              const void* __restrict__ ie,
                                              const int* __restrict__ flag,
                                              float* __restrict__ E) {
    int idx = blockIdx.x * 256 + threadIdx.x;           // over NN*64
    if (idx >= NN * DD) return;
    int row = idx >> 6;
    bool isU = row < N_USERC;
    int si = isU ? idx : idx - N_USERC * DD;
    float v;
    if (*flag) {
        v = bf2f(isU ? ((const ushort_t*)ue)[si] : ((const ushort_t*)ie)[si]);
    } else {
        v = isU ? ((const float*)ue)[si] : ((const float*)ie)[si];
    }
    E[idx] = v;
}

// ---- E (fp32) -> Eb (bf16 gather copy); runs after phaseB (Eb aliases binned) ----
__global__ __launch_bounds__(256) void k_tobf(const float* __restrict__ E,
                                              ushort_t* __restrict__ Eb) {
    int idx = blockIdx.x * 256 + threadIdx.x;
    if (idx < NN * DD) Eb[idx] = f2bf(E[idx]);
}

// ---- zero the 147 bucket counters ----
__global__ __launch_bounds__(256) void k_zb(int* __restrict__ bucket_cnt) {
    if (threadIdx.x < NBKT) bucket_cnt[threadIdx.x] = 0;
}

// ---- bucket histogram: 147 buckets of 1024 rows ----
__global__ __launch_bounds__(256) void k_bhist(const int* __restrict__ rows,
                                               int* __restrict__ bucket_cnt) {
    __shared__ int h[NBKT];
    int t = threadIdx.x;
    if (t < NBKT) h[t] = 0;
    __syncthreads();
    int e0 = blockIdx.x * 4096;
#pragma unroll
    for (int i = 0; i < 16; i++) {
        int e = e0 + t + i * 256;
        if (e < NNZC) atomicAdd(&h[rows[e] >> 10], 1);
    }
    __syncthreads();
    if (t < NBKT && h[t]) atomicAdd(&bucket_cnt[t], h[t]);
}

// ---- exclusive scan of 147 bucket counts; seed bases/cursors ----
__global__ __launch_bounds__(256) void k_bscan(const int* __restrict__ bucket_cnt,
                                               int* __restrict__ gbase,
                                               int* __restrict__ gcursor,
                                               int* __restrict__ row_ptr) {
    __shared__ int s[256];
    int t = threadIdx.x;
    int v = (t < NBKT) ? bucket_cnt[t] : 0;
    s[t] = v; __syncthreads();
    for (int off = 1; off < 256; off <<= 1) {
        int x = (t >= off) ? s[t - off] : 0;
        __syncthreads();
        s[t] += x;
        __syncthreads();
    }
    if (t < NBKT) { int ex = s[t] - v; gbase[t] = ex; gcursor[t] = ex; }
    if (t == 0) { gbase[NBKT] = NNZC; row_ptr[NN] = NNZC; }
}

// ---- phase A: partition edges into 147 row-buckets ----
__global__ __launch_bounds__(256) void k_phaseA(const int* __restrict__ rows,
                                                const int* __restrict__ cols,
                                                const void* __restrict__ vals,
                                                const int* __restrict__ flag,
                                                int* __restrict__ gcursor,
                                                int2* __restrict__ binned) {
    __shared__ int hist[NBKT], base_[NBKT], lcur[NBKT];
    int t = threadIdx.x;
    int e0 = blockIdx.x * 4096;
    if (t < NBKT) { hist[t] = 0; lcur[t] = 0; }
    __syncthreads();
    int myrow[16];
#pragma unroll
    for (int i = 0; i < 16; i++) {
        int e = e0 + t + i * 256;
        int r = -1;
        if (e < NNZC) { r = rows[e]; atomicAdd(&hist[r >> 10], 1); }
        myrow[i] = r;
    }
    __syncthreads();
    if (t < NBKT && hist[t] > 0) base_[t] = atomicAdd(&gcursor[t], hist[t]);
    __syncthreads();
    int isbf = *flag;
#pragma unroll
    for (int i = 0; i < 16; i++) {
        int e = e0 + t + i * 256;
        if (e < NNZC) {
            int r = myrow[i];
            int bkt = r >> 10;
            int off = atomicAdd(&lcur[bkt], 1);
            int pos = base_[bkt] + off;
            int c = cols[e];
            float v = isbf ? bf2f(((const ushort_t*)vals)[e]) : ((const float*)vals)[e];
            // pack: row_local(10b) << 18 | col(18b); val bits separate
            binned[pos] = make_int2(((r & 1023) << 18) | c, __float_as_int(v));
        }
    }
}

// ---- phase B: one block per bucket; exact CSR slice via LDS hist+scan+cursor ----
__global__ __launch_bounds__(256) void k_phaseB(const int* __restrict__ gbase,
                                                const int2* __restrict__ binned,
                                                int2* __restrict__ ep,
                                                int* __restrict__ row_ptr) {
    __shared__ int rc[1024];    // counts -> inclusive scan
    __shared__ int rofs[1024];  // counts copy -> exclusive -> cursor
    int b = blockIdx.x, t = threadIdx.x;
    int s = gbase[b], e = gbase[b + 1];
    for (int i = t; i < 1024; i += 256) rc[i] = 0;
    __syncthreads();
    for (int i = s + t; i < e; i += 256)
        atomicAdd(&rc[binned[i].x >> 18], 1);
    __syncthreads();
    for (int i = t; i < 1024; i += 256) rofs[i] = rc[i];
    __syncthreads();
    for (int off = 1; off < 1024; off <<= 1) {
        int v[4];
#pragma unroll
        for (int j = 0; j < 4; j++) {
            int idx = t + j * 256;
            v[j] = (idx >= off) ? rc[idx - off] : 0;
        }
        __syncthreads();
#pragma unroll
        for (int j = 0; j < 4; j++) rc[t + j * 256] += v[j];
        __syncthreads();
    }
    for (int i = t; i < 1024; i += 256) {
        int ex = rc[i] - rofs[i];          // exclusive
        int gr = b * 1024 + i;
        if (gr < NN) row_ptr[gr] = s + ex;
        rofs[i] = ex;                      // becomes cursor
    }
    __syncthreads();
    for (int i = s + t; i < e; i += 256) {
        int2 en = binned[i];
        int rl = en.x >> 18;
        int c  = en.x & 0x3FFFF;
        int off = atomicAdd(&rofs[rl], 1);
        ep[s + off] = make_int2(c, en.y);
    }
}

// ---- SpMM v3: lane = (oct = edge slot, d8 = 8 dims). One uint4 gather covers
// 8 bf16 dims of one edge's row; a wave instruction covers 8 edges; x2 unroll
// puts 16 edges in flight per waitcnt window (round-8 evidence: latency-bound,
// not bytes-bound). ep reads: per-oct dwordx2, 64 contiguous B/wave. ----
__global__ __launch_bounds__(256) void k_spmm(const int* __restrict__ row_ptr,
                                              const int2* __restrict__ ep,
                                              const ushort_t* __restrict__ Eb,
                                              float* __restrict__ LE) {
    int wv = threadIdx.x >> 6;
    int r = blockIdx.x * 4 + wv;               // 37500*4 = 150000 exact
    int lane = threadIdx.x & 63;
    int oct = lane >> 3;                       // edge slot 0..7
    int d8  = (lane & 7) * 8;                  // dims d8..d8+7
    int s = __builtin_amdgcn_readfirstlane(row_ptr[r]);
    int e = __builtin_amdgcn_readfirstlane(row_ptr[r + 1]);
    float acc[8];
#pragma unroll
    for (int k = 0; k < 8; k++) acc[k] = 0.f;
    for (int i = s; i < e; i += 16) {
#pragma unroll
        for (int v = 0; v < 2; v++) {
            int idx = i + v * 8 + oct;
            bool valid = idx < e;
            int j = valid ? idx : s;
            int2 pv = ep[j];
            float w = valid ? __int_as_float(pv.y) : 0.f;
            uint4 q = *(const uint4*)(Eb + (size_t)pv.x * DD + d8);
            acc[0] = fmaf(w, __uint_as_float(q.x << 16),          acc[0]);
            acc[1] = fmaf(w, __uint_as_float(q.x & 0xffff0000u),  acc[1]);
            acc[2] = fmaf(w, __uint_as_float(q.y << 16),          acc[2]);
            acc[3] = fmaf(w, __uint_as_float(q.y & 0xffff0000u),  acc[3]);
            acc[4] = fmaf(w, __uint_as_float(q.z << 16),          acc[4]);
            acc[5] = fmaf(w, __uint_as_float(q.z & 0xffff0000u),  acc[5]);
            acc[6] = fmaf(w, __uint_as_float(q.w << 16),          acc[6]);
            acc[7] = fmaf(w, __uint_as_float(q.w & 0xffff0000u),  acc[7]);
        }
    }
    // fold the 8 octs: butterfly over lane bits 3,4,5
#pragma unroll
    for (int m = 8; m < 64; m <<= 1)
#pragma unroll
        for (int k = 0; k < 8; k++) acc[k] += __shfl_xor(acc[k], m, 64);
    if (oct == 0) {
        float* dst = LE + (size_t)r * DD + d8;
        *(float4*)dst       = make_float4(acc[0], acc[1], acc[2], acc[3]);
        *(float4*)(dst + 4) = make_float4(acc[4], acc[5], acc[6], acc[7]);
    }
}

// ---- dense v2: lane = col; W columns in VGPRs; x broadcast via v_readlane.
// Updates both E (fp32, truth) and Eb (bf16 gather copy). ----
__global__ __launch_bounds__(256) void k_dense2(const float* __restrict__ LE,
                                                float* __restrict__ E,
                                                ushort_t* __restrict__ Eb,
                                                const void* __restrict__ W1b,
                                                const void* __restrict__ W2b,
                                                const void* __restrict__ b1b,
                                                const void* __restrict__ b2b,
                                                const int* __restrict__ flag,
                                                int layer) {
    int lane = threadIdx.x & 63;
    int gw = (blockIdx.x * 256 + threadIdx.x) >> 6;
    int nw = (gridDim.x * 256) >> 6;
    int isbf = *flag;

    float w1r[64], w2r[64];
    size_t Wo = (size_t)layer * 4096 + lane;
#pragma unroll
    for (int k = 0; k < 64; k++) {
        w1r[k] = isbf ? bf2f(((const ushort_t*)W1b)[Wo + (size_t)k * 64])
                      : ((const float*)W1b)[Wo + (size_t)k * 64];
        w2r[k] = isbf ? bf2f(((const ushort_t*)W2b)[Wo + (size_t)k * 64])
                      : ((const float*)W2b)[Wo + (size_t)k * 64];
    }
    size_t bo = (size_t)layer * 64 + lane;
    float bias = (isbf ? bf2f(((const ushort_t*)b1b)[bo]) : ((const float*)b1b)[bo])
               + (isbf ? bf2f(((const ushort_t*)b2b)[bo]) : ((const float*)b2b)[bo]);

    for (int r0 = gw * 2; r0 < NN; r0 += nw * 2) {
        const float* LA = LE + (size_t)r0 * DD;
        float*       EA = E  + (size_t)r0 * DD;
        float leA = LA[lane],      eA = EA[lane];
        float leB = LA[DD + lane], eB = EA[DD + lane];
        float x1A = leA + eA, x2A = leA * eA;
        float x1B = leB + eB, x2B = leB * eB;
        float a0 = 0.f, a1 = 0.f, c0 = 0.f, c1 = 0.f;
#pragma unroll
        for (int k = 0; k < 64; k += 2) {
            a0 = fmaf(rlane(x1A, k),     w1r[k],     a0);
            a0 = fmaf(rlane(x2A, k),     w2r[k],     a0);
            a1 = fmaf(rlane(x1A, k + 1), w1r[k + 1], a1);
            a1 = fmaf(rlane(x2A, k + 1), w2r[k + 1], a1);
            c0 = fmaf(rlane(x1B, k),     w1r[k],     c0);
            c0 = fmaf(rlane(x2B, k),     w2r[k],     c0);
            c1 = fmaf(rlane(x1B, k + 1), w1r[k + 1], c1);
            c1 = fmaf(rlane(x2B, k + 1), w2r[k + 1], c1);
        }
        float hA = a0 + a1 + bias; hA = (hA >= 0.f) ? hA : 0.2f * hA;
        float hB = c0 + c1 + bias; hB = (hB >= 0.f) ? hB : 0.2f * hB;
        EA[lane] = hA;
        EA[DD + lane] = hB;
        Eb[(size_t)r0 * DD + lane] = f2bf(hA);
        Eb[(size_t)r0 * DD + DD + lane] = f2bf(hB);
    }
}

static __device__ __forceinline__ int rid_to_node(int rid,
                                                  const int* users, const int* pos, const int* neg) {
    if (rid < BB)      return users[rid] - 1;
    if (rid < 2 * BB)  return N_USERC + pos[rid - BB] - 1;
    return N_USERC + neg[rid - 2 * BB] - 1;
}

// ---- slice 0 of output: raw initial embedding (fp32) of gathered rows ----
__global__ __launch_bounds__(256) void k_outslice0(const float* __restrict__ E,
                                                   const int* __restrict__ users,
                                                   const int* __restrict__ pos,
                                                   const int* __restrict__ neg,
                                                   float* __restrict__ out) {
    int rid  = blockIdx.x * 4 + (threadIdx.x >> 6);
    int lane = threadIdx.x & 63;
    if (rid >= NRID) return;
    int node = rid_to_node(rid, users, pos, neg);
    out[(size_t)rid * 256 + lane] = E[(size_t)node * DD + lane];
}

// ---- slice l+1: normalized current E of gathered rows (fp32) ----
__global__ __launch_bounds__(256) void k_outnorm(const float* __restrict__ E,
                                                 const int* __restrict__ users,
                                                 const int* __restrict__ pos,
                                                 const int* __restrict__ neg,
                                                 float* __restrict__ out,
                                                 int cbase) {
    int rid  = blockIdx.x * 4 + (threadIdx.x >> 6);
    int lane = threadIdx.x & 63;
    if (rid >= NRID) return;
    int node = rid_to_node(rid, users, pos, neg);
    float v = E[(size_t)node * DD + lane];
    float p2 = v * v;
    for (int m = 1; m < 64; m <<= 1) p2 += __shfl_xor(p2, m, 64);
    float nr = fmaxf(sqrtf(p2), 1e-12f);
    out[(size_t)rid * 256 + cbase + lane] = v / nr;
}

extern "C" void kernel_launch(void* const* d_in, const int* in_sizes, int n_in,
                              void* d_out, int out_size, void* d_ws, size_t ws_size,
                              hipStream_t stream) {
    const void* ue   = d_in[0];
    const void* ie   = d_in[1];
    const void* ev   = d_in[2];
    const void* W1   = d_in[3];
    const void* b1   = d_in[4];
    const void* W2   = d_in[5];
    const void* b2   = d_in[6];
    const int*  ei   = (const int*)d_in[7];
    const int*  usr  = (const int*)d_in[8];
    const int*  posi = (const int*)d_in[9];
    const int*  negi = (const int*)d_in[10];
    float*      out  = (float*)d_out;          // reference output dtype = fp32

    const int* rows = ei;
    const int* cols = ei + NNZC;

    // workspace carve — total ~116 MB (Eb aliases binned: binned is dead after phaseB)
    char* w = (char*)d_ws;
    float*  E         = (float*)w;  w += (size_t)NN * DD * 4;    // 38.4 MB
    float*  LE        = (float*)w;  w += (size_t)NN * DD * 4;    // 38.4 MB
    int2*   binned    = (int2*)w;   w += (size_t)NNZC * 8;       // 19.2 MB
    ushort_t* Eb      = (ushort_t*)binned;                       // alias (19.2 MB need)
    int2*   ep        = (int2*)w;   w += (size_t)NNZC * 8;       // 19.2 MB
    int*    row_ptr   = (int*)w;    w += 600320;                 // NN+1 ints padded
    int*    gbase     = (int*)w;    w += 1024;                   // NBKT+1
    int*    gcursor   = (int*)w;    w += 1024;
    int*    bucket_cnt= (int*)w;    w += 1024;
    int*    flag      = (int*)w;    w += 256;

    k_sniff<<<1, 64, 0, stream>>>((const unsigned int*)ue, flag);
    k_init<<<37500, 256, 0, stream>>>(ue, ie, flag, E);
    k_zb<<<1, 256, 0, stream>>>(bucket_cnt);
    k_bhist<<<NABLK, 256, 0, stream>>>(rows, bucket_cnt);
    k_bscan<<<1, 256, 0, stream>>>(bucket_cnt, gbase, gcursor, row_ptr);
    k_phaseA<<<NABLK, 256, 0, stream>>>(rows, cols, ev, flag, gcursor, binned);
    k_phaseB<<<NBKT, 256, 0, stream>>>(gbase, binned, ep, row_ptr);
    k_tobf<<<37500, 256, 0, stream>>>(E, Eb);      // after phaseB: binned is dead

    k_outslice0<<<3072, 256, 0, stream>>>(E, usr, posi, negi, out);

    for (int l = 0; l < NLAYER; l++) {
        k_spmm<<<37500, 256, 0, stream>>>(row_ptr, ep, Eb, LE);
        k_dense2<<<768, 256, 0, stream>>>(LE, E, Eb, W1, W2, b1, b2, flag, l);
        k_outnorm<<<3072, 256, 0, stream>>>(E, usr, posi, negi, out, 64 * (l + 1));
    }
}